// Round 1
// baseline (20.864 us; speedup 1.0000x reference)
//
#include <hip/hip_runtime.h>
#include <hip/hip_bf16.h>

// out[n] = exp(-0.5 * (x[n]-mu)^T cov (x[n]-mu)), x:[N,2] f32, mu:[2], cov:[2,2]
// Memory-bound streaming kernel: 2x float4 loads (4 points) + 1 float4 store per iter.

__global__ void gauss_pdf_kernel(const float4* __restrict__ x4,
                                 const float* __restrict__ mu,
                                 const float* __restrict__ cov,
                                 float4* __restrict__ out4,
                                 int n4) {
    // Broadcast (wave-uniform) scalar loads; cached, negligible traffic.
    const float mx  = mu[0];
    const float my  = mu[1];
    const float c00 = cov[0];
    const float cxy = cov[1] + cov[2];
    const float c11 = cov[3];

    int idx    = blockIdx.x * blockDim.x + threadIdx.x;
    int stride = gridDim.x * blockDim.x;

    for (int i = idx; i < n4; i += stride) {
        // 4 points per iteration: x4[2i] = {x0,y0,x1,y1}, x4[2i+1] = {x2,y2,x3,y3}
        float4 a = x4[2 * i];
        float4 b = x4[2 * i + 1];
        float4 r;

        float dx = a.x - mx, dy = a.y - my;
        r.x = __expf(-0.5f * (c00 * dx * dx + cxy * dx * dy + c11 * dy * dy));

        dx = a.z - mx; dy = a.w - my;
        r.y = __expf(-0.5f * (c00 * dx * dx + cxy * dx * dy + c11 * dy * dy));

        dx = b.x - mx; dy = b.y - my;
        r.z = __expf(-0.5f * (c00 * dx * dx + cxy * dx * dy + c11 * dy * dy));

        dx = b.z - mx; dy = b.w - my;
        r.w = __expf(-0.5f * (c00 * dx * dx + cxy * dx * dy + c11 * dy * dy));

        out4[i] = r;
    }
}

extern "C" void kernel_launch(void* const* d_in, const int* in_sizes, int n_in,
                              void* d_out, int out_size, void* d_ws, size_t ws_size,
                              hipStream_t stream) {
    const float* x   = (const float*)d_in[0];   // [N,2]
    const float* mu  = (const float*)d_in[1];   // [2]
    const float* cov = (const float*)d_in[2];   // [2,2]
    float* out       = (float*)d_out;           // [N]

    const int n  = out_size;        // N points
    const int n4 = n / 4;           // N = 8388608 divisible by 4

    const int block = 256;
    int grid = (n4 + block - 1) / block;
    if (grid > 2048) grid = 2048;   // grid-stride, ~8 blocks/CU

    gauss_pdf_kernel<<<grid, block, 0, stream>>>(
        (const float4*)x, mu, cov, (float4*)out, n4);

    // Tail (N not divisible by 4) — not hit for N=8388608, but keep it correct.
    // Handled by a tiny scalar pass if needed:
    int rem = n - n4 * 4;
    if (rem > 0) {
        // single-block scalar tail
        struct TailLauncher {
        };
        // Use a lambda-free tail kernel launch:
        extern __global__ void gauss_pdf_tail(const float*, const float*, const float*, float*, int, int);
        gauss_pdf_tail<<<1, 64, 0, stream>>>(x, mu, cov, out, n4 * 4, n);
    }
}

__global__ void gauss_pdf_tail(const float* __restrict__ x,
                               const float* __restrict__ mu,
                               const float* __restrict__ cov,
                               float* __restrict__ out,
                               int start, int n) {
    const float mx  = mu[0];
    const float my  = mu[1];
    const float c00 = cov[0];
    const float cxy = cov[1] + cov[2];
    const float c11 = cov[3];
    for (int i = start + threadIdx.x; i < n; i += blockDim.x) {
        float dx = x[2 * i] - mx, dy = x[2 * i + 1] - my;
        out[i] = __expf(-0.5f * (c00 * dx * dx + cxy * dx * dy + c11 * dy * dy));
    }
}